// Round 11
// baseline (330.895 us; speedup 1.0000x reference)
//
#include <hip/hip_runtime.h>

#define DI __device__ __forceinline__

DI float silu_f(float x) { return x / (1.f + __expf(-x)); }
DI float sigmoid_f(float x) { return 1.f / (1.f + __expf(-x)); }
DI int reflect_i(int i, int n) { if (i < 0) i = -i; if (i >= n) i = 2 * n - 2 - i; return i; }

// K1: bilinear resize (2,3,1024,1024) -> (2,3,256,256), align-corners style.
__global__ __launch_bounds__(256) void k_resize(const float* __restrict__ img,
                                                float* __restrict__ x) {
    __shared__ float r0s[1024], r1s[1024];
    const int oy = blockIdx.x & 255;
    const int bc = blockIdx.x >> 8;  // 0..5
    float py = oy * (1023.f / 255.f);
    int iy0 = (int)py; if (iy0 > 1022) iy0 = 1022;
    float fy = py - (float)iy0;
    const float* p0 = img + ((size_t)bc * 1024 + iy0) * 1024;
    ((float4*)r0s)[threadIdx.x] = ((const float4*)p0)[threadIdx.x];
    ((float4*)r1s)[threadIdx.x] = ((const float4*)(p0 + 1024))[threadIdx.x];
    __syncthreads();
    const int ox = threadIdx.x;
    float px = ox * (1023.f / 255.f);
    int ix0 = (int)px; if (ix0 > 1022) ix0 = 1022;
    float fx = px - (float)ix0;
    float a00 = r0s[ix0], a01 = r0s[ix0 + 1];
    float a10 = r1s[ix0], a11 = r1s[ix0 + 1];
    float r0v = a00 + fy * (a10 - a00);
    float r1v = a01 + fy * (a11 - a01);
    x[((size_t)bc * 256 + oy) * 256 + ox] = r0v + fx * (r1v - r0v);
}

// LDS-staged 3x3 stride-2 reflect conv + SiLU.
// Block = (bb, row-group of ROWS out rows, oc-group of OCB ocs).
// Weights staged once; input staged per ICB-chunk as coalesced float4 bursts
// (y-reflect applied at stage time); inner loop reads LDS only.
template<int CIN, int HIN, int WIN, int COUT, int ROWS, int OCB, int ICB, int PXPT>
__global__ __launch_bounds__(256) void k_conv_lds(const float* __restrict__ in,
                                                  const float* __restrict__ w,
                                                  const float* __restrict__ bias,
                                                  float* __restrict__ out) {
    constexpr int HOUT = HIN / 2, WOUT = WIN / 2;
    constexpr int NR = 2 * ROWS + 1;
    constexpr int WINP = WIN + 4;             // pad keeps f4 align, spreads banks
    constexpr int NRG = HOUT / ROWS;
    constexpr int NOCG = COUT / OCB;
    constexpr int XT = WOUT / PXPT;           // threads along x
    static_assert(ROWS * XT == 256, "block = 256 threads");
    static_assert(CIN % ICB == 0, "ICB divides CIN");

    __shared__ float sIn[ICB * NR * WINP];
    __shared__ float sw[OCB * CIN * 12];

    const int tid = threadIdx.x;
    const int ocg = blockIdx.x % NOCG;
    const int rg  = (blockIdx.x / NOCG) % NRG;
    const int bb  = blockIdx.x / (NOCG * NRG);

    {
        const float* src = w + (size_t)(ocg * OCB) * CIN * 9;
        for (int i = tid; i < OCB * CIN * 9; i += 256)
            sw[(i / 9) * 12 + (i % 9)] = src[i];
    }

    const int xt = tid % XT;
    const int r  = tid / XT;
    const int x0 = xt * PXPT;
    const int oy0 = rg * ROWS;
    const int row0 = 2 * oy0 - 1;

    int xs[3 * PXPT];
#pragma unroll
    for (int p = 0; p < PXPT; ++p)
#pragma unroll
        for (int kx = 0; kx < 3; ++kx)
            xs[kx * PXPT + p] = reflect_i(2 * (x0 + p) + kx - 1, WIN);

    float acc[OCB][PXPT];
#pragma unroll
    for (int o = 0; o < OCB; ++o)
#pragma unroll
        for (int p = 0; p < PXPT; ++p) acc[o][p] = 0.f;

    constexpr int W4 = WIN / 4;
    constexpr int UN = ICB * NR * W4;

    for (int ic0 = 0; ic0 < CIN; ic0 += ICB) {
        __syncthreads();
        for (int u = tid; u < UN; u += 256) {
            const int p   = u / (NR * W4);
            const int rem = u % (NR * W4);
            const int lr  = rem / W4;
            const int c4  = rem % W4;
            const int grow = reflect_i(row0 + lr, HIN);
            const float4 v = *(const float4*)(in +
                ((size_t)(bb * CIN + ic0 + p) * HIN + grow) * WIN + 4 * c4);
            *(float4*)&sIn[(p * NR + lr) * WINP + 4 * c4] = v;
        }
        __syncthreads();

        for (int ic = 0; ic < ICB; ++ic) {
            const float* ibase = sIn + (ic * NR + 2 * r) * WINP;
            float t[3][3 * PXPT];
#pragma unroll
            for (int ky = 0; ky < 3; ++ky) {
                const float* rp = ibase + ky * WINP;
#pragma unroll
                for (int j = 0; j < 3 * PXPT; ++j) t[ky][j] = rp[xs[j]];
            }
#pragma unroll
            for (int o = 0; o < OCB; ++o) {
                const float* wp = sw + ((size_t)o * CIN + ic0 + ic) * 12;
#pragma unroll
                for (int ky = 0; ky < 3; ++ky)
#pragma unroll
                    for (int kx = 0; kx < 3; ++kx)
#pragma unroll
                        for (int p = 0; p < PXPT; ++p)
                            acc[o][p] = fmaf(t[ky][kx * PXPT + p], wp[ky * 3 + kx], acc[o][p]);
            }
        }
    }

#pragma unroll
    for (int o = 0; o < OCB; ++o) {
        const int oc = ocg * OCB + o;
        const float bv = bias[oc];
        float* op = out + ((size_t)(bb * COUT + oc) * HOUT + oy0 + r) * WOUT + x0;
        if (PXPT == 2) {
            float2 v = make_float2(silu_f(acc[o][0] + bv), silu_f(acc[o][1] + bv));
            *(float2*)op = v;
        } else {
#pragma unroll
            for (int p = 0; p < PXPT; ++p) op[p] = silu_f(acc[o][p] + bv);
        }
    }
}

// K6: fused avg-pool + concat -> feat (2,480,8,8). Wave-coalesced.
__global__ __launch_bounds__(256) void k_pool(const float* __restrict__ c1,
                                              const float* __restrict__ c2,
                                              const float* __restrict__ c3,
                                              const float* __restrict__ c4,
                                              float* __restrict__ feat) {
    const int tid = threadIdx.x;
    const int W = blockIdx.x * 4 + (tid >> 6);
    const int lane = tid & 63;
    if (W < 512) {
        int bb = W >> 8, rem = W & 255;
        int c = rem >> 3, y = rem & 7;
        const float* p = c1 + ((size_t)bb * 32 + c) * 128 * 128 + (y * 16) * 128 + lane * 2;
        float s = 0.f;
#pragma unroll
        for (int r = 0; r < 16; ++r) {
            float2 v = *(const float2*)(p + r * 128);
            s += v.x + v.y;
        }
        s += __shfl_xor(s, 1, 64);
        s += __shfl_xor(s, 2, 64);
        s += __shfl_xor(s, 4, 64);
        if ((lane & 7) == 0)
            feat[((size_t)bb * 480 + c) * 64 + y * 8 + (lane >> 3)] = s * (1.f / 256.f);
    } else if (W < 1536) {
        int V = W - 512;
        int bb = V >> 9, rem = V & 511;
        int c = rem >> 3, y = rem & 7;
        const float* p = c2 + ((size_t)bb * 64 + c) * 64 * 64 + (y * 8) * 64 + lane;
        float s = 0.f;
#pragma unroll
        for (int r = 0; r < 8; ++r) s += p[r * 64];
        s += __shfl_xor(s, 1, 64);
        s += __shfl_xor(s, 2, 64);
        s += __shfl_xor(s, 4, 64);
        if ((lane & 7) == 0)
            feat[((size_t)bb * 480 + 32 + c) * 64 + y * 8 + (lane >> 3)] = s * (1.f / 64.f);
    } else if (W < 1792) {
        int T = (W - 1536) * 64 + lane;  // [0, 16384)
        int bb = T >> 13, rem = T & 8191;
        int c = rem >> 6, y = (rem >> 3) & 7, x = rem & 7;
        const float* p = c3 + ((size_t)bb * 128 + c) * 32 * 32 + (y * 4) * 32 + x * 4;
        float s = 0.f;
#pragma unroll
        for (int r = 0; r < 4; ++r) {
            float4 v = *(const float4*)(p + r * 32);
            s += v.x + v.y + v.z + v.w;
        }
        feat[((size_t)bb * 480 + 96 + c) * 64 + y * 8 + x] = s * (1.f / 16.f);
    } else {
        int T = (W - 1792) * 64 + lane;  // [0, 32768)
        int bb = T >> 14, rem = T & 16383;
        int c = rem >> 6, y = (rem >> 3) & 7, x = rem & 7;
        const float* p = c4 + ((size_t)bb * 256 + c) * 16 * 16 + (y * 2) * 16 + x * 2;
        float2 v0 = *(const float2*)p;
        float2 v1 = *(const float2*)(p + 16);
        feat[((size_t)bb * 480 + 224 + c) * 64 + y * 8 + x] = (v0.x + v0.y + v1.x + v1.y) * 0.25f;
    }
}

// K7: lin1 = 3x3 reflect conv 480->128 on 8x8 + SiLU.
__global__ __launch_bounds__(512) void k_lin1(const float* __restrict__ feat,
                                              const float* __restrict__ w,
                                              const float* __restrict__ bias,
                                              float* __restrict__ h1) {
    __shared__ float sw[480 * 9];
    __shared__ float sred[8][64];
    const int tid = threadIdx.x;
    const int bb = blockIdx.x >> 7;
    const int oc = blockIdx.x & 127;
    {
        const float* src = w + (size_t)oc * 480 * 9;
        for (int i = tid; i < 480 * 9; i += 512) sw[i] = src[i];
    }
    const int wave = tid >> 6;
    const int lane = tid & 63;
    const int py = lane >> 3, px = lane & 7;
    int srcl[9];
#pragma unroll
    for (int ky = 0; ky < 3; ++ky)
#pragma unroll
        for (int kx = 0; kx < 3; ++kx)
            srcl[ky * 3 + kx] = reflect_i(py + ky - 1, 8) * 8 + reflect_i(px + kx - 1, 8);
    __syncthreads();

    const float* fp = feat + (size_t)bb * 480 * 64;
    float acc = 0.f;
    for (int ic = wave * 60; ic < wave * 60 + 60; ++ic) {
        float v = fp[ic * 64 + lane];
        const float* wp = sw + ic * 9;
#pragma unroll
        for (int j = 0; j < 9; ++j)
            acc = fmaf(__shfl(v, srcl[j], 64), wp[j], acc);
    }
    sred[wave][lane] = acc;
    __syncthreads();
    if (wave == 0) {
        float s = 0.f;
#pragma unroll
        for (int wv = 0; wv < 8; ++wv) s += sred[wv][lane];
        h1[((size_t)bb * 128 + oc) * 64 + lane] = silu_f(s + bias[oc]);
    }
}

// K9: fused lin2 + sigmoid + bilinear-upsample + LUT interp + weighted sum + clip.
__global__ __launch_bounds__(256) void k_apply(const float* __restrict__ img,
                                               const float* __restrict__ h1,
                                               const float* __restrict__ l2w,
                                               const float* __restrict__ l2b,
                                               const float* __restrict__ luts,
                                               float* __restrict__ out) {
    __shared__ float2 slut2[9 * 256];
    __shared__ float swl[9 * 64];
    __shared__ float su4[4 * 72];
    const int tid = threadIdx.x;
    const int bc = blockIdx.y;  // 0..5
    const int bb = bc / 3, c = bc % 3;
    const int wave = tid >> 6, pix = tid & 63;

    for (int i = tid; i < 9 * 256; i += 256) {
        int k = i >> 8, j = i & 255;
        const float* lp = luts + (size_t)(c * 9 + k) * 256;
        float v0 = lp[j];
        float v1 = lp[j < 255 ? j + 1 : 255];
        slut2[i] = make_float2(v0, v1);
    }
    {
        const float* hp = h1 + (size_t)bb * 128 * 64;
        for (int o = wave; o < 9; o += 4) {
            const float* wp = l2w + (size_t)(c * 9 + o) * 128;
            float s = l2b[c * 9 + o];
            for (int ic = 0; ic < 128; ++ic) s = fmaf(hp[ic * 64 + pix], wp[ic], s);
            swl[o * 64 + pix] = sigmoid_f(s);
        }
    }
    __syncthreads();
    for (int i = tid; i < 288; i += 256) {
        int rr = i / 72, rem = i % 72;
        int k = rem >> 3, xx = rem & 7;
        int h = blockIdx.x * 4 + rr;
        float py = h * (7.f / 1023.f);
        int iy0 = (int)py; if (iy0 > 6) iy0 = 6;
        float fy = py - (float)iy0;
        float a = swl[k * 64 + iy0 * 8 + xx];
        float b = swl[k * 64 + iy0 * 8 + 8 + xx];
        su4[i] = fmaf(fy, b - a, a);
    }
    __syncthreads();

    const int x0 = tid * 4;
    float fx[4]; int sel[4]; int cbase;
    {
        float p0 = x0 * (7.f / 1023.f);
        int ib = (int)p0; if (ib > 6) ib = 6;
        cbase = ib;
#pragma unroll
        for (int p = 0; p < 4; ++p) {
            float pxf = (x0 + p) * (7.f / 1023.f);
            int i = (int)pxf; if (i > 6) i = 6;
            sel[p] = i - cbase;
            fx[p] = pxf - (float)i;
        }
    }
    const size_t plane = ((size_t)bb * 3 + c) * 1024;
    const int h0 = blockIdx.x * 4;

    float4 v = ((const float4*)(img + (plane + h0) * 1024))[tid];
    for (int rr = 0; rr < 4; ++rr) {
        float4 vn = v;
        if (rr < 3) vn = ((const float4*)(img + (plane + h0 + rr + 1) * 1024))[tid];
        float xin[4] = {v.x, v.y, v.z, v.w};
        int i0[4]; float fr[4]; float acc[4] = {0.f, 0.f, 0.f, 0.f};
#pragma unroll
        for (int p = 0; p < 4; ++p) {
            float pv = fminf(fmaxf(xin[p], 0.f), 1.f) * 255.f;
            int i = (int)pv; if (i > 254) i = 254;
            i0[p] = i; fr[p] = pv - (float)i;
        }
        const float* srow = su4 + rr * 72;
#pragma unroll
        for (int k = 0; k < 9; ++k) {
            float s0 = srow[k * 8 + cbase];
            float s1 = srow[k * 8 + cbase + 1];
            float s2 = (cbase < 6) ? srow[k * 8 + cbase + 2] : s1;
            const float2* lrow = slut2 + k * 256;
#pragma unroll
            for (int p = 0; p < 4; ++p) {
                float a = sel[p] ? s1 : s0;
                float b = sel[p] ? s2 : s1;
                float wt = fmaf(fx[p], b - a, a);
                float2 l = lrow[i0[p]];
                acc[p] = fmaf(wt, fmaf(fr[p], l.y - l.x, l.x), acc[p]);
            }
        }
        float4 o4 = make_float4(fminf(fmaxf(acc[0], 0.f), 1.f),
                                fminf(fmaxf(acc[1], 0.f), 1.f),
                                fminf(fmaxf(acc[2], 0.f), 1.f),
                                fminf(fmaxf(acc[3], 0.f), 1.f));
        ((float4*)(out + (plane + h0 + rr) * 1024))[tid] = o4;
        v = vn;
    }
}

extern "C" void kernel_launch(void* const* d_in, const int* in_sizes, int n_in,
                              void* d_out, int out_size, void* d_ws, size_t ws_size,
                              hipStream_t stream) {
    const float* img     = (const float*)d_in[0];
    const float* conv1_w = (const float*)d_in[1];
    const float* conv1_b = (const float*)d_in[2];
    const float* conv2_w = (const float*)d_in[3];
    const float* conv2_b = (const float*)d_in[4];
    const float* conv3_w = (const float*)d_in[5];
    const float* conv3_b = (const float*)d_in[6];
    const float* conv4_w = (const float*)d_in[7];
    const float* conv4_b = (const float*)d_in[8];
    const float* lin1_w  = (const float*)d_in[9];
    const float* lin1_b  = (const float*)d_in[10];
    const float* lin2_w  = (const float*)d_in[11];
    const float* lin2_b  = (const float*)d_in[12];
    const float* luts    = (const float*)d_in[13];
    float* out = (float*)d_out;

    float* ws = (float*)d_ws;
    float* x_rs = ws;            ws += 2 * 3 * 256 * 256;
    float* c1   = ws;            ws += 2 * 32 * 128 * 128;
    float* c2   = ws;            ws += 2 * 64 * 64 * 64;
    float* c3   = ws;            ws += 2 * 128 * 32 * 32;
    float* c4   = ws;            ws += 2 * 256 * 16 * 16;
    float* feat = ws;            ws += 2 * 480 * 8 * 8;
    float* h1   = ws;            ws += 2 * 128 * 8 * 8;

    const int B = 256;
    k_resize<<<6 * 256, B, 0, stream>>>(img, x_rs);
    // conv1: <3,256,256,32, ROWS4,OCB16,ICB3,PXPT2>  grid 2*32*2   = 128
    k_conv_lds<3, 256, 256, 32, 4, 16, 3, 2><<<128, B, 0, stream>>>(x_rs, conv1_w, conv1_b, c1);
    // conv2: <32,128,128,64, ROWS4,OCB8,ICB8,PXPT1>  grid 2*16*8   = 256
    k_conv_lds<32, 128, 128, 64, 4, 8, 8, 1><<<256, B, 0, stream>>>(c1, conv2_w, conv2_b, c2);
    // conv3: <64,64,64,128, ROWS8,OCB8,ICB8,PXPT1>   grid 2*4*16   = 128
    k_conv_lds<64, 64, 64, 128, 8, 8, 8, 1><<<128, B, 0, stream>>>(c2, conv3_w, conv3_b, c3);
    // conv4: <128,32,32,256, ROWS16,OCB4,ICB8,PXPT1> grid 2*1*64   = 128
    k_conv_lds<128, 32, 32, 256, 16, 4, 8, 1><<<128, B, 0, stream>>>(c3, conv4_w, conv4_b, c4);
    k_pool<<<576, B, 0, stream>>>(c1, c2, c3, c4, feat);
    k_lin1<<<256, 512, 0, stream>>>(feat, lin1_w, lin1_b, h1);
    dim3 agrid(256, 6);
    k_apply<<<agrid, B, 0, stream>>>(img, h1, lin2_w, lin2_b, luts, out);
}

// Round 12
// 248.428 us; speedup vs baseline: 1.3320x; 1.3320x over previous
//
#include <hip/hip_runtime.h>

#define DI __device__ __forceinline__

DI float silu_f(float x) { return x / (1.f + __expf(-x)); }
DI float sigmoid_f(float x) { return 1.f / (1.f + __expf(-x)); }
DI int reflect_i(int i, int n) { if (i < 0) i = -i; if (i >= n) i = 2 * n - 2 - i; return i; }

// K1: bilinear resize (2,3,1024,1024) -> (2,3,256,256), align-corners style.
__global__ __launch_bounds__(256) void k_resize(const float* __restrict__ img,
                                                float* __restrict__ x) {
    __shared__ float r0s[1024], r1s[1024];
    const int oy = blockIdx.x & 255;
    const int bc = blockIdx.x >> 8;  // 0..5
    float py = oy * (1023.f / 255.f);
    int iy0 = (int)py; if (iy0 > 1022) iy0 = 1022;
    float fy = py - (float)iy0;
    const float* p0 = img + ((size_t)bc * 1024 + iy0) * 1024;
    ((float4*)r0s)[threadIdx.x] = ((const float4*)p0)[threadIdx.x];
    ((float4*)r1s)[threadIdx.x] = ((const float4*)(p0 + 1024))[threadIdx.x];
    __syncthreads();
    const int ox = threadIdx.x;
    float px = ox * (1023.f / 255.f);
    int ix0 = (int)px; if (ix0 > 1022) ix0 = 1022;
    float fx = px - (float)ix0;
    float a00 = r0s[ix0], a01 = r0s[ix0 + 1];
    float a10 = r1s[ix0], a11 = r1s[ix0 + 1];
    float r0v = a00 + fy * (a10 - a00);
    float r1v = a01 + fy * (a11 - a01);
    x[((size_t)bc * 256 + oy) * 256 + ox] = r0v + fx * (r1v - r0v);
}

// 3x3 stride-2 reflect conv + SiLU. Wave handles OCW ocs; lane = out px.
// Depth-4 register prefetch pipeline over ic when CIN%4==0 (conv2); simple
// path otherwise (conv1, CIN=3).
template<int CIN, int HIN, int WIN, int COUT, int OCW>
__global__ __launch_bounds__(256) void k_conv_woc(const float* __restrict__ in,
                                                  const float* __restrict__ w,
                                                  const float* __restrict__ bias,
                                                  float* __restrict__ out) {
    constexpr int HOUT = HIN / 2, WOUT = WIN / 2;
    constexpr int NB_PX = 2 * HOUT * WOUT / 64;
    constexpr int NOC = 4 * OCW;
    constexpr int PL = HIN * WIN;

    __shared__ float sw[NOC * CIN * 12];
    const int tid = threadIdx.x;
    const int ocu = blockIdx.x / NB_PX;
    const int bpx = blockIdx.x % NB_PX;
    {
        const float* src = w + (size_t)(ocu * NOC) * CIN * 9;
        for (int i = tid; i < NOC * CIN * 9; i += 256)
            sw[(i / 9) * 12 + (i % 9)] = src[i];
    }
    __syncthreads();

    const int wave = tid >> 6, lane = tid & 63;
    const int pxu = bpx * 64 + lane;
    const int ox = pxu % WOUT;
    const int oy = (pxu / WOUT) % HOUT;
    const int bb = pxu / (WOUT * HOUT);

    int off[9];
#pragma unroll
    for (int ky = 0; ky < 3; ++ky) {
        int ry = reflect_i(2 * oy + ky - 1, HIN) * WIN;
#pragma unroll
        for (int kx = 0; kx < 3; ++kx)
            off[ky * 3 + kx] = ry + reflect_i(2 * ox + kx - 1, WIN);
    }

    float acc[OCW];
#pragma unroll
    for (int o = 0; o < OCW; ++o) acc[o] = 0.f;
    const float* swb = sw + (size_t)(wave * OCW) * CIN * 12;
    const float* base = in + (size_t)bb * CIN * PL;

    if constexpr (CIN % 4 == 0) {
        float t0[9], t1[9], t2[9], t3[9];
#pragma unroll
        for (int j = 0; j < 9; ++j) t0[j] = base[off[j]];
#pragma unroll
        for (int j = 0; j < 9; ++j) t1[j] = base[PL + off[j]];
#pragma unroll
        for (int j = 0; j < 9; ++j) t2[j] = base[2 * PL + off[j]];
#pragma unroll
        for (int j = 0; j < 9; ++j) t3[j] = base[3 * PL + off[j]];
        const float* ldb = base + 4 * PL;
        for (int ic = 0; ic < CIN; ic += 4) {
            const bool more = (ic + 4 < CIN);
#pragma unroll
            for (int o = 0; o < OCW; ++o) {
                const float* wp = swb + ((size_t)o * CIN + ic) * 12;
#pragma unroll
                for (int j = 0; j < 9; ++j) acc[o] = fmaf(t0[j], wp[j], acc[o]);
            }
            if (more) {
#pragma unroll
                for (int j = 0; j < 9; ++j) t0[j] = ldb[off[j]];
            }
#pragma unroll
            for (int o = 0; o < OCW; ++o) {
                const float* wp = swb + ((size_t)o * CIN + ic + 1) * 12;
#pragma unroll
                for (int j = 0; j < 9; ++j) acc[o] = fmaf(t1[j], wp[j], acc[o]);
            }
            if (more) {
#pragma unroll
                for (int j = 0; j < 9; ++j) t1[j] = ldb[PL + off[j]];
            }
#pragma unroll
            for (int o = 0; o < OCW; ++o) {
                const float* wp = swb + ((size_t)o * CIN + ic + 2) * 12;
#pragma unroll
                for (int j = 0; j < 9; ++j) acc[o] = fmaf(t2[j], wp[j], acc[o]);
            }
            if (more) {
#pragma unroll
                for (int j = 0; j < 9; ++j) t2[j] = ldb[2 * PL + off[j]];
            }
#pragma unroll
            for (int o = 0; o < OCW; ++o) {
                const float* wp = swb + ((size_t)o * CIN + ic + 3) * 12;
#pragma unroll
                for (int j = 0; j < 9; ++j) acc[o] = fmaf(t3[j], wp[j], acc[o]);
            }
            if (more) {
#pragma unroll
                for (int j = 0; j < 9; ++j) t3[j] = ldb[3 * PL + off[j]];
                ldb += 4 * PL;
            }
        }
    } else {
#pragma unroll
        for (int ic = 0; ic < CIN; ++ic) {
            float t[9];
#pragma unroll
            for (int j = 0; j < 9; ++j) t[j] = base[off[j]];
#pragma unroll
            for (int o = 0; o < OCW; ++o) {
                const float* wp = swb + ((size_t)o * CIN + ic) * 12;
#pragma unroll
                for (int j = 0; j < 9; ++j) acc[o] = fmaf(t[j], wp[j], acc[o]);
            }
            base += PL;
        }
    }

#pragma unroll
    for (int o = 0; o < OCW; ++o) {
        const int oc = ocu * NOC + wave * OCW + o;
        out[(((size_t)bb * COUT + oc) * HOUT + oy) * WOUT + ox] =
            silu_f(acc[o] + bias[oc]);
    }
}

// 3x3 stride-2 reflect conv + SiLU, wave-level 4-way K-split (conv3/conv4),
// depth-4 register prefetch pipeline.
template<int CIN, int HIN, int WIN, int COUT, int OC_PER>
__global__ __launch_bounds__(256) void k_conv_w4(const float* __restrict__ in,
                                                 const float* __restrict__ w,
                                                 const float* __restrict__ bias,
                                                 float* __restrict__ out) {
    constexpr int HOUT = HIN / 2, WOUT = WIN / 2;
    constexpr int NB_PX = 2 * HOUT * WOUT / 64;
    constexpr int ICC = CIN / 4;
    constexpr int PL = HIN * WIN;
    static_assert(ICC % 4 == 0, "ICC multiple of 4");

    __shared__ float sw[OC_PER * CIN * 12];
    __shared__ float sred[4][OC_PER][64];
    const int tid = threadIdx.x;
    const int ocu = blockIdx.x / NB_PX;
    const int bpx = blockIdx.x % NB_PX;
    {
        const float* src = w + (size_t)(ocu * OC_PER) * CIN * 9;
        for (int i = tid; i < OC_PER * CIN * 9; i += 256)
            sw[(i / 9) * 12 + (i % 9)] = src[i];
    }
    __syncthreads();

    const int kc = tid >> 6;
    const int lane = tid & 63;
    const int pxu = bpx * 64 + lane;
    const int ox = pxu % WOUT;
    const int oy = (pxu / WOUT) % HOUT;
    const int bb = pxu / (WOUT * HOUT);

    int off[9];
#pragma unroll
    for (int ky = 0; ky < 3; ++ky) {
        int ry = reflect_i(2 * oy + ky - 1, HIN) * WIN;
#pragma unroll
        for (int kx = 0; kx < 3; ++kx)
            off[ky * 3 + kx] = ry + reflect_i(2 * ox + kx - 1, WIN);
    }

    float acc[OC_PER];
#pragma unroll
    for (int o = 0; o < OC_PER; ++o) acc[o] = 0.f;
    const float* base = in + ((size_t)bb * CIN + kc * ICC) * PL;

    float t0[9], t1[9], t2[9], t3[9];
#pragma unroll
    for (int j = 0; j < 9; ++j) t0[j] = base[off[j]];
#pragma unroll
    for (int j = 0; j < 9; ++j) t1[j] = base[PL + off[j]];
#pragma unroll
    for (int j = 0; j < 9; ++j) t2[j] = base[2 * PL + off[j]];
#pragma unroll
    for (int j = 0; j < 9; ++j) t3[j] = base[3 * PL + off[j]];
    const float* ldb = base + 4 * PL;

    for (int icl = 0; icl < ICC; icl += 4) {
        const int ic = kc * ICC + icl;
        const bool more = (icl + 4 < ICC);
#pragma unroll
        for (int o = 0; o < OC_PER; ++o) {
            const float* wp = sw + ((size_t)o * CIN + ic) * 12;
#pragma unroll
            for (int j = 0; j < 9; ++j) acc[o] = fmaf(t0[j], wp[j], acc[o]);
        }
        if (more) {
#pragma unroll
            for (int j = 0; j < 9; ++j) t0[j] = ldb[off[j]];
        }
#pragma unroll
        for (int o = 0; o < OC_PER; ++o) {
            const float* wp = sw + ((size_t)o * CIN + ic + 1) * 12;
#pragma unroll
            for (int j = 0; j < 9; ++j) acc[o] = fmaf(t1[j], wp[j], acc[o]);
        }
        if (more) {
#pragma unroll
            for (int j = 0; j < 9; ++j) t1[j] = ldb[PL + off[j]];
        }
#pragma unroll
        for (int o = 0; o < OC_PER; ++o) {
            const float* wp = sw + ((size_t)o * CIN + ic + 2) * 12;
#pragma unroll
            for (int j = 0; j < 9; ++j) acc[o] = fmaf(t2[j], wp[j], acc[o]);
        }
        if (more) {
#pragma unroll
            for (int j = 0; j < 9; ++j) t2[j] = ldb[2 * PL + off[j]];
        }
#pragma unroll
        for (int o = 0; o < OC_PER; ++o) {
            const float* wp = sw + ((size_t)o * CIN + ic + 3) * 12;
#pragma unroll
            for (int j = 0; j < 9; ++j) acc[o] = fmaf(t3[j], wp[j], acc[o]);
        }
        if (more) {
#pragma unroll
            for (int j = 0; j < 9; ++j) t3[j] = ldb[3 * PL + off[j]];
            ldb += 4 * PL;
        }
    }

#pragma unroll
    for (int o = 0; o < OC_PER; ++o) sred[kc][o][lane] = acc[o];
    __syncthreads();
    if (kc < OC_PER) {
        const int o = kc;
        const int oc = ocu * OC_PER + o;
        float s = sred[0][o][lane] + sred[1][o][lane] + sred[2][o][lane] + sred[3][o][lane];
        out[(((size_t)bb * COUT + oc) * HOUT + oy) * WOUT + ox] = silu_f(s + bias[oc]);
    }
}

// K6: fused avg-pool + concat -> feat (2,480,8,8). Wave-coalesced.
__global__ __launch_bounds__(256) void k_pool(const float* __restrict__ c1,
                                              const float* __restrict__ c2,
                                              const float* __restrict__ c3,
                                              const float* __restrict__ c4,
                                              float* __restrict__ feat) {
    const int tid = threadIdx.x;
    const int W = blockIdx.x * 4 + (tid >> 6);
    const int lane = tid & 63;
    if (W < 512) {
        int bb = W >> 8, rem = W & 255;
        int c = rem >> 3, y = rem & 7;
        const float* p = c1 + ((size_t)bb * 32 + c) * 128 * 128 + (y * 16) * 128 + lane * 2;
        float s = 0.f;
#pragma unroll
        for (int r = 0; r < 16; ++r) {
            float2 v = *(const float2*)(p + r * 128);
            s += v.x + v.y;
        }
        s += __shfl_xor(s, 1, 64);
        s += __shfl_xor(s, 2, 64);
        s += __shfl_xor(s, 4, 64);
        if ((lane & 7) == 0)
            feat[((size_t)bb * 480 + c) * 64 + y * 8 + (lane >> 3)] = s * (1.f / 256.f);
    } else if (W < 1536) {
        int V = W - 512;
        int bb = V >> 9, rem = V & 511;
        int c = rem >> 3, y = rem & 7;
        const float* p = c2 + ((size_t)bb * 64 + c) * 64 * 64 + (y * 8) * 64 + lane;
        float s = 0.f;
#pragma unroll
        for (int r = 0; r < 8; ++r) s += p[r * 64];
        s += __shfl_xor(s, 1, 64);
        s += __shfl_xor(s, 2, 64);
        s += __shfl_xor(s, 4, 64);
        if ((lane & 7) == 0)
            feat[((size_t)bb * 480 + 32 + c) * 64 + y * 8 + (lane >> 3)] = s * (1.f / 64.f);
    } else if (W < 1792) {
        int T = (W - 1536) * 64 + lane;  // [0, 16384)
        int bb = T >> 13, rem = T & 8191;
        int c = rem >> 6, y = (rem >> 3) & 7, x = rem & 7;
        const float* p = c3 + ((size_t)bb * 128 + c) * 32 * 32 + (y * 4) * 32 + x * 4;
        float s = 0.f;
#pragma unroll
        for (int r = 0; r < 4; ++r) {
            float4 v = *(const float4*)(p + r * 32);
            s += v.x + v.y + v.z + v.w;
        }
        feat[((size_t)bb * 480 + 96 + c) * 64 + y * 8 + x] = s * (1.f / 16.f);
    } else {
        int T = (W - 1792) * 64 + lane;  // [0, 32768)
        int bb = T >> 14, rem = T & 16383;
        int c = rem >> 6, y = (rem >> 3) & 7, x = rem & 7;
        const float* p = c4 + ((size_t)bb * 256 + c) * 16 * 16 + (y * 2) * 16 + x * 2;
        float2 v0 = *(const float2*)p;
        float2 v1 = *(const float2*)(p + 16);
        feat[((size_t)bb * 480 + 224 + c) * 64 + y * 8 + x] = (v0.x + v0.y + v1.x + v1.y) * 0.25f;
    }
}

// K7: lin1 = 3x3 reflect conv 480->128 on 8x8 + SiLU.
__global__ __launch_bounds__(512) void k_lin1(const float* __restrict__ feat,
                                              const float* __restrict__ w,
                                              const float* __restrict__ bias,
                                              float* __restrict__ h1) {
    __shared__ float sw[480 * 9];
    __shared__ float sred[8][64];
    const int tid = threadIdx.x;
    const int bb = blockIdx.x >> 7;
    const int oc = blockIdx.x & 127;
    {
        const float* src = w + (size_t)oc * 480 * 9;
        for (int i = tid; i < 480 * 9; i += 512) sw[i] = src[i];
    }
    const int wave = tid >> 6;
    const int lane = tid & 63;
    const int py = lane >> 3, px = lane & 7;
    int srcl[9];
#pragma unroll
    for (int ky = 0; ky < 3; ++ky)
#pragma unroll
        for (int kx = 0; kx < 3; ++kx)
            srcl[ky * 3 + kx] = reflect_i(py + ky - 1, 8) * 8 + reflect_i(px + kx - 1, 8);
    __syncthreads();

    const float* fp = feat + (size_t)bb * 480 * 64;
    float acc = 0.f;
    for (int ic = wave * 60; ic < wave * 60 + 60; ++ic) {
        float v = fp[ic * 64 + lane];
        const float* wp = sw + ic * 9;
#pragma unroll
        for (int j = 0; j < 9; ++j)
            acc = fmaf(__shfl(v, srcl[j], 64), wp[j], acc);
    }
    sred[wave][lane] = acc;
    __syncthreads();
    if (wave == 0) {
        float s = 0.f;
#pragma unroll
        for (int wv = 0; wv < 8; ++wv) s += sred[wv][lane];
        h1[((size_t)bb * 128 + oc) * 64 + lane] = silu_f(s + bias[oc]);
    }
}

// K9: fused lin2 + sigmoid + bilinear-upsample + LUT interp + weighted sum + clip.
__global__ __launch_bounds__(256) void k_apply(const float* __restrict__ img,
                                               const float* __restrict__ h1,
                                               const float* __restrict__ l2w,
                                               const float* __restrict__ l2b,
                                               const float* __restrict__ luts,
                                               float* __restrict__ out) {
    __shared__ float2 slut2[9 * 256];
    __shared__ float swl[9 * 64];
    __shared__ float su4[4 * 72];
    const int tid = threadIdx.x;
    const int bc = blockIdx.y;  // 0..5
    const int bb = bc / 3, c = bc % 3;
    const int wave = tid >> 6, pix = tid & 63;

    for (int i = tid; i < 9 * 256; i += 256) {
        int k = i >> 8, j = i & 255;
        const float* lp = luts + (size_t)(c * 9 + k) * 256;
        float v0 = lp[j];
        float v1 = lp[j < 255 ? j + 1 : 255];
        slut2[i] = make_float2(v0, v1);
    }
    {
        const float* hp = h1 + (size_t)bb * 128 * 64;
        for (int o = wave; o < 9; o += 4) {
            const float* wp = l2w + (size_t)(c * 9 + o) * 128;
            float s = l2b[c * 9 + o];
            for (int ic = 0; ic < 128; ++ic) s = fmaf(hp[ic * 64 + pix], wp[ic], s);
            swl[o * 64 + pix] = sigmoid_f(s);
        }
    }
    __syncthreads();
    for (int i = tid; i < 288; i += 256) {
        int rr = i / 72, rem = i % 72;
        int k = rem >> 3, xx = rem & 7;
        int h = blockIdx.x * 4 + rr;
        float py = h * (7.f / 1023.f);
        int iy0 = (int)py; if (iy0 > 6) iy0 = 6;
        float fy = py - (float)iy0;
        float a = swl[k * 64 + iy0 * 8 + xx];
        float b = swl[k * 64 + iy0 * 8 + 8 + xx];
        su4[i] = fmaf(fy, b - a, a);
    }
    __syncthreads();

    const int x0 = tid * 4;
    float fx[4]; int sel[4]; int cbase;
    {
        float p0 = x0 * (7.f / 1023.f);
        int ib = (int)p0; if (ib > 6) ib = 6;
        cbase = ib;
#pragma unroll
        for (int p = 0; p < 4; ++p) {
            float pxf = (x0 + p) * (7.f / 1023.f);
            int i = (int)pxf; if (i > 6) i = 6;
            sel[p] = i - cbase;
            fx[p] = pxf - (float)i;
        }
    }
    const size_t plane = ((size_t)bb * 3 + c) * 1024;
    const int h0 = blockIdx.x * 4;

    float4 v = ((const float4*)(img + (plane + h0) * 1024))[tid];
    for (int rr = 0; rr < 4; ++rr) {
        float4 vn = v;
        if (rr < 3) vn = ((const float4*)(img + (plane + h0 + rr + 1) * 1024))[tid];
        float xin[4] = {v.x, v.y, v.z, v.w};
        int i0[4]; float fr[4]; float acc[4] = {0.f, 0.f, 0.f, 0.f};
#pragma unroll
        for (int p = 0; p < 4; ++p) {
            float pv = fminf(fmaxf(xin[p], 0.f), 1.f) * 255.f;
            int i = (int)pv; if (i > 254) i = 254;
            i0[p] = i; fr[p] = pv - (float)i;
        }
        const float* srow = su4 + rr * 72;
#pragma unroll
        for (int k = 0; k < 9; ++k) {
            float s0 = srow[k * 8 + cbase];
            float s1 = srow[k * 8 + cbase + 1];
            float s2 = (cbase < 6) ? srow[k * 8 + cbase + 2] : s1;
            const float2* lrow = slut2 + k * 256;
#pragma unroll
            for (int p = 0; p < 4; ++p) {
                float a = sel[p] ? s1 : s0;
                float b = sel[p] ? s2 : s1;
                float wt = fmaf(fx[p], b - a, a);
                float2 l = lrow[i0[p]];
                acc[p] = fmaf(wt, fmaf(fr[p], l.y - l.x, l.x), acc[p]);
            }
        }
        float4 o4 = make_float4(fminf(fmaxf(acc[0], 0.f), 1.f),
                                fminf(fmaxf(acc[1], 0.f), 1.f),
                                fminf(fmaxf(acc[2], 0.f), 1.f),
                                fminf(fmaxf(acc[3], 0.f), 1.f));
        ((float4*)(out + (plane + h0 + rr) * 1024))[tid] = o4;
        v = vn;
    }
}

extern "C" void kernel_launch(void* const* d_in, const int* in_sizes, int n_in,
                              void* d_out, int out_size, void* d_ws, size_t ws_size,
                              hipStream_t stream) {
    const float* img     = (const float*)d_in[0];
    const float* conv1_w = (const float*)d_in[1];
    const float* conv1_b = (const float*)d_in[2];
    const float* conv2_w = (const float*)d_in[3];
    const float* conv2_b = (const float*)d_in[4];
    const float* conv3_w = (const float*)d_in[5];
    const float* conv3_b = (const float*)d_in[6];
    const float* conv4_w = (const float*)d_in[7];
    const float* conv4_b = (const float*)d_in[8];
    const float* lin1_w  = (const float*)d_in[9];
    const float* lin1_b  = (const float*)d_in[10];
    const float* lin2_w  = (const float*)d_in[11];
    const float* lin2_b  = (const float*)d_in[12];
    const float* luts    = (const float*)d_in[13];
    float* out = (float*)d_out;

    float* ws = (float*)d_ws;
    float* x_rs = ws;            ws += 2 * 3 * 256 * 256;
    float* c1   = ws;            ws += 2 * 32 * 128 * 128;
    float* c2   = ws;            ws += 2 * 64 * 64 * 64;
    float* c3   = ws;            ws += 2 * 128 * 32 * 32;
    float* c4   = ws;            ws += 2 * 256 * 16 * 16;
    float* feat = ws;            ws += 2 * 480 * 8 * 8;
    float* h1   = ws;            ws += 2 * 128 * 8 * 8;

    const int B = 256;
    k_resize<<<6 * 256, B, 0, stream>>>(img, x_rs);
    // R6-best configs + depth-4 register prefetch:
    // conv1: 512 px-blocks * 4 oc-octets = 2048 (simple path, CIN=3)
    k_conv_woc<3, 256, 256, 32, 2><<<2048, B, 0, stream>>>(x_rs, conv1_w, conv1_b, c1);
    // conv2: 128 px-blocks * 8 oc-octets = 1024 (pipelined)
    k_conv_woc<32, 128, 128, 64, 2><<<1024, B, 0, stream>>>(c1, conv2_w, conv2_b, c2);
    // conv3: 32 px-blocks * 64 = 2048 (pipelined)
    k_conv_w4<64, 64, 64, 128, 2><<<2048, B, 0, stream>>>(c2, conv3_w, conv3_b, c3);
    // conv4: 8 px-blocks * 128 = 1024 (pipelined)
    k_conv_w4<128, 32, 32, 256, 2><<<1024, B, 0, stream>>>(c3, conv4_w, conv4_b, c4);
    k_pool<<<576, B, 0, stream>>>(c1, c2, c3, c4, feat);
    k_lin1<<<256, 512, 0, stream>>>(feat, lin1_w, lin1_b, h1);
    dim3 agrid(256, 6);
    k_apply<<<agrid, B, 0, stream>>>(img, h1, lin2_w, lin2_b, luts, out);
}